// Round 6
// baseline (277.741 us; speedup 1.0000x reference)
//
#include <hip/hip_runtime.h>

#define NNODES 100000
#define NEDGES 1600000
#define HID 16
#define MSG 16
#define NTYPE 16
#define NCLS 64

#define BSH 7
#define NBK ((NNODES + 127) >> 7)           // 782 buckets of 128 nodes (dst>>7)
#define CHSZ 8192
#define NCH ((NEDGES + CHSZ - 1) / CHSZ)    // 196 edge chunks
#define M_SCAN (NBK * NCH)                  // 153,272
#define SCH 1024
#define NSB ((M_SCAN + SCH - 1) / SCH)      // 150

// At2 layout: [ty][i][h], row stride 20 floats (16B-aligned, bank-spread for b128)
#define ASTR 20
#define ATY  320

#define RECCAP 2560   // LDS staging capacity for a bucket's record segment

__device__ __forceinline__ float sigmoid_f(float x) {
    return 1.0f / (1.0f + __expf(-x));
}
__device__ __forceinline__ float tanh_f(float x) {
    x = fminf(fmaxf(x, -15.0f), 15.0f);
    float e = __expf(2.0f * x);
    return (e - 1.0f) / (e + 1.0f);
}

// ---------------------------------------------------------------------------
// Phase A: per-chunk bucket histogram (LDS atomics only)
// ---------------------------------------------------------------------------
__global__ __launch_bounds__(1024) void hist_k(const int* __restrict__ dst,
                                               int* __restrict__ cntmat) {
    __shared__ int cnt[NBK];
    const int t = threadIdx.x, ch = blockIdx.x;
    for (int b = t; b < NBK; b += 1024) cnt[b] = 0;
    __syncthreads();
    #pragma unroll
    for (int k = 0; k < CHSZ / 1024; k++) {
        int e = ch * CHSZ + k * 1024 + t;
        if (e < NEDGES) atomicAdd(&cnt[dst[e] >> BSH], 1);
    }
    __syncthreads();
    for (int b = t; b < NBK; b += 1024) cntmat[b * NCH + ch] = cnt[b];
}

// ---------------------------------------------------------------------------
// Phase B: exclusive scan of cntmat (bucket-major), in place. 3 kernels.
// ---------------------------------------------------------------------------
__global__ __launch_bounds__(256) void scan_bsum(const int* __restrict__ x,
                                                 int* __restrict__ bsum) {
    const int t = threadIdx.x;
    int base = blockIdx.x * SCH + t * 4;
    int s = 0;
    #pragma unroll
    for (int q = 0; q < 4; q++) {
        int idx = base + q;
        if (idx < M_SCAN) s += x[idx];
    }
    #pragma unroll
    for (int d = 32; d > 0; d >>= 1) s += __shfl_down(s, d, 64);
    __shared__ int ws[4];
    int lane = t & 63, w = t >> 6;
    if (lane == 0) ws[w] = s;
    __syncthreads();
    if (t == 0) bsum[blockIdx.x] = ws[0] + ws[1] + ws[2] + ws[3];
}

__global__ __launch_bounds__(256) void scan_top(int* __restrict__ bsum) {
    const int t = threadIdx.x;
    int v = (t < NSB) ? bsum[t] : 0;
    int lane = t & 63, w = t >> 6;
    int s = v;
    #pragma unroll
    for (int d = 1; d < 64; d <<= 1) {
        int u = __shfl_up(s, d, 64);
        if (lane >= d) s += u;
    }
    __shared__ int ws[4];
    if (lane == 63) ws[w] = s;
    __syncthreads();
    int base = 0;
    #pragma unroll
    for (int q = 0; q < 4; q++) if (q < w) base += ws[q];
    if (t < NSB) bsum[t] = base + s - v;
}

__global__ __launch_bounds__(256) void scan_write(const int* __restrict__ bsum,
                                                  int* __restrict__ x) {
    const int t = threadIdx.x;
    int base = blockIdx.x * SCH + t * 4;
    int v[4]; int ts = 0;
    #pragma unroll
    for (int q = 0; q < 4; q++) {
        int idx = base + q;
        v[q] = (idx < M_SCAN) ? x[idx] : 0;
        ts += v[q];
    }
    int lane = t & 63, w = t >> 6;
    int s = ts;
    #pragma unroll
    for (int d = 1; d < 64; d <<= 1) {
        int u = __shfl_up(s, d, 64);
        if (lane >= d) s += u;
    }
    __shared__ int ws[4];
    if (lane == 63) ws[w] = s;
    __syncthreads();
    int wbase = 0;
    #pragma unroll
    for (int q = 0; q < 4; q++) if (q < w) wbase += ws[q];
    int run = bsum[blockIdx.x] + wbase + (s - ts);
    #pragma unroll
    for (int q = 0; q < 4; q++) {
        int idx = base + q;
        if (idx < M_SCAN) x[idx] = run;
        run += v[q];
    }
}

// ---------------------------------------------------------------------------
// Phase C: scatter into bucket-grouped records. LDS cursors, zero global
// atomics, segment-clustered writes. rec = src | et<<17 | (dst&127)<<21
// ---------------------------------------------------------------------------
__global__ __launch_bounds__(1024) void scatter_k(const int* __restrict__ src,
                                                  const int* __restrict__ dst,
                                                  const int* __restrict__ et,
                                                  const int* __restrict__ offmat,
                                                  int* __restrict__ rec) {
    __shared__ int offc[NBK];
    const int t = threadIdx.x, ch = blockIdx.x;
    for (int b = t; b < NBK; b += 1024) offc[b] = offmat[b * NCH + ch];
    __syncthreads();
    #pragma unroll
    for (int k = 0; k < CHSZ / 1024; k++) {
        int e = ch * CHSZ + k * 1024 + t;
        if (e < NEDGES) {
            int d = dst[e];
            int b = d >> BSH;
            int pos = atomicAdd(&offc[b], 1);
            rec[pos] = src[e] | (et[e] << 17) | ((d & 127) << 21);
        }
    }
}

// ---------------------------------------------------------------------------
// Phase D: per-bucket aggregation with ASYNC global->LDS feat staging.
// 512 threads = 8 waves; each wave owns interleaved 16-edge chunks and
// double-buffers them via global_load_lds (1 vmem inst stages 16 edges).
// Source-quarter rotation (rot = row>>2) makes the compute-phase
// ds_read_b128s bank-conflict-free across the wave's 4 groups.
// ---------------------------------------------------------------------------
#define EDGE_MSG(F0, F1, F2, F3, tyv, ldv)                                  \
    {                                                                        \
        const float4* pa_ = (const float4*)(At2 + (tyv) * ATY + i * ASTR);   \
        float4 A0_ = pa_[0], A1_ = pa_[1], A2_ = pa_[2], A3_ = pa_[3];       \
        float m_;                                                            \
        m_  = A0_.x*(F0).x + A0_.y*(F0).y + A0_.z*(F0).z + A0_.w*(F0).w;     \
        m_ += A1_.x*(F1).x + A1_.y*(F1).y + A1_.z*(F1).z + A1_.w*(F1).w;     \
        m_ += A2_.x*(F2).x + A2_.y*(F2).y + A2_.z*(F2).z + A2_.w*(F2).w;     \
        m_ += A3_.x*(F3).x + A3_.y*(F3).y + A3_.z*(F3).z + A3_.w*(F3).w;     \
        atomicAdd(&acc[(ldv) * 17 + i], m_);                                 \
    }

__global__ __launch_bounds__(512) void agg_k(const float* __restrict__ feat,
                                             const int* __restrict__ offmat,
                                             const int* __restrict__ rec,
                                             const float* __restrict__ edge_emb,
                                             float* __restrict__ magg) {
    __shared__ float At2[NTYPE * ATY];      // 20480 B
    __shared__ float acc[128 * 17];         // 8704 B
    __shared__ int   recs[RECCAP];          // 10240 B
    __shared__ float fbuf[8 * 2 * 256];     // 16384 B: per wave 2 bufs x 16 rows x 16 f
    const int t = threadIdx.x, b = blockIdx.x;

    #pragma unroll
    for (int idx = t; idx < NTYPE * MSG * HID; idx += 512) {
        int ty = idx >> 8, rem = idx & 255, ii = rem >> 4, h = rem & 15;
        At2[ty * ATY + ii * ASTR + h] = edge_emb[idx];
    }
    for (int k = t; k < 128 * 17; k += 512) acc[k] = 0.0f;

    const int jb  = offmat[b * NCH];
    const int je  = (b == NBK - 1) ? NEDGES : offmat[(b + 1) * NCH];
    const int len = je - jb;
    const int lcap = len < RECCAP ? len : RECCAP;
    for (int k = t; k < lcap; k += 512) recs[k] = rec[jb + k];
    __syncthreads();

    const int w    = t >> 6;        // wave 0..7
    const int lane = t & 63;
    const int g    = lane >> 4;     // group 0..3 (16 lanes each)
    const int i    = lane & 15;

    float* fb = fbuf + w * 512;     // this wave's two 256-float buffers
    const int ntot = (lcap + 15) >> 4;   // 16-edge chunks in staged region

    // Stage chunk c into buffer bufi: ONE global_load_lds per wave.
    // Lane l: row R=l>>2 (edge c*16+R), quarter q=l&3, source quarter
    // rotated by rot=R>>2 so compute reads are bank-conflict-free.
    #define STAGE(c, bufi)                                                    \
    {                                                                         \
        int e_ = ((c) << 4) + (lane >> 2);                                    \
        if (e_ < lcap) {                                                      \
            int r_ = recs[e_];                                                \
            const float* gp_ = feat + (size_t)(r_ & 0x1FFFF) * HID            \
                               + ((((lane & 3) + (lane >> 4)) & 3) << 2);     \
            __builtin_amdgcn_global_load_lds(gp_, fb + (bufi) * 256, 16, 0, 0);\
        }                                                                     \
    }

    // Compute chunk c from buffer bufi: group g handles rows 4g..4g+3.
    // Logical quarter q of row R sits at position (q - g) & 3.
    #define COMPUTE(c, bufi)                                                  \
    {                                                                         \
        _Pragma("unroll")                                                     \
        for (int s_ = 0; s_ < 4; s_++) {                                      \
            int e_ = ((c) << 4) + (g << 2) + s_;                              \
            if (e_ < lcap) {                                                  \
                int r_  = recs[e_];                                           \
                int ty_ = (r_ >> 17) & 15;                                    \
                int ld_ = r_ >> 21;                                           \
                const float4* fr_ = (const float4*)(fb + (bufi) * 256         \
                                      + (((g << 2) + s_) << 4));              \
                const float4* pa_ = (const float4*)(At2 + ty_ * ATY + i * ASTR);\
                float m_ = 0.0f;                                              \
                _Pragma("unroll")                                             \
                for (int q_ = 0; q_ < 4; q_++) {                              \
                    float4 F_ = fr_[(q_ - g) & 3];                            \
                    float4 A_ = pa_[q_];                                      \
                    m_ += A_.x*F_.x + A_.y*F_.y + A_.z*F_.z + A_.w*F_.w;      \
                }                                                             \
                atomicAdd(&acc[ld_ * 17 + i], m_);                            \
            }                                                                 \
        }                                                                     \
    }

    // Prologue: two chunks in flight.
    if (w < ntot)     STAGE(w, 0);
    if (w + 8 < ntot) STAGE(w + 8, 1);
    int buf = 0;
    for (int c = w; c < ntot; c += 8) {
        if (c + 8 < ntot) { asm volatile("s_waitcnt vmcnt(1)" ::: "memory"); }
        else              { asm volatile("s_waitcnt vmcnt(0)" ::: "memory"); }
        __builtin_amdgcn_sched_barrier(0);
        COMPUTE(c, buf);
        if (c + 16 < ntot) STAGE(c + 16, buf);
        buf ^= 1;
    }

    // Overflow tail (only if segment > RECCAP): serial from global.
    {
        const int gg = t >> 4;   // 32 groups across the block
        for (int j = lcap + gg; j < len; j += 32) {
            int r0 = rec[jb + j];
            int s0 = r0 & 0x1FFFF, ty0 = (r0 >> 17) & 15, ld0 = r0 >> 21;
            const float4* p0 = (const float4*)(feat + (size_t)s0 * HID);
            float4 F00 = p0[0], F01 = p0[1], F02 = p0[2], F03 = p0[3];
            EDGE_MSG(F00, F01, F02, F03, ty0, ld0)
        }
    }
    __syncthreads();

    const int nb = b << BSH;
    #pragma unroll
    for (int k = t; k < 128 * 16; k += 512) {
        int ln = k >> 4, ii = k & 15;
        int n = nb + ln;
        if (n < NNODES) magg[(size_t)n * MSG + ii] = acc[ln * 17 + ii];
    }
    #undef STAGE
    #undef COMPUTE
}

// ---------------------------------------------------------------------------
// Fallback atomic edge kernel (only if ws too small)
// ---------------------------------------------------------------------------
__global__ __launch_bounds__(256) void ggnn_edge(
    const float* __restrict__ feat,
    const int* __restrict__ src,
    const int* __restrict__ dst,
    const int* __restrict__ etype,
    const float* __restrict__ edge_emb,
    float* __restrict__ magg)
{
    __shared__ float At[NTYPE * MSG * HID];
    for (int idx = threadIdx.x; idx < NTYPE * MSG * HID; idx += 256) {
        int ty = idx >> 8, rem = idx & 255, i = rem >> 4, hh = rem & 15;
        At[(ty << 8) | (hh << 4) | i] = edge_emb[idx];
    }
    __syncthreads();
    const long long total = (long long)NEDGES * MSG;
    for (long long w = (long long)blockIdx.x * 256 + threadIdx.x; w < total;
         w += (long long)gridDim.x * 256) {
        const int e = (int)(w >> 4);
        const int i = (int)(w & 15);
        const int s = src[e];
        const int d = dst[e];
        const int ty = etype[e];
        const float4* fp = (const float4*)(feat + (size_t)s * HID);
        const float4 f0 = fp[0], f1 = fp[1], f2 = fp[2], f3 = fp[3];
        const float* a = At + (ty << 8) + i;
        float m;
        m  = a[0*16]*f0.x + a[1*16]*f0.y + a[2*16]*f0.z + a[3*16]*f0.w;
        m += a[4*16]*f1.x + a[5*16]*f1.y + a[6*16]*f1.z + a[7*16]*f1.w;
        m += a[8*16]*f2.x + a[9*16]*f2.y + a[10*16]*f2.z + a[11*16]*f2.w;
        m += a[12*16]*f3.x + a[13*16]*f3.y + a[14*16]*f3.z + a[15*16]*f3.w;
        atomicAdd(magg + (size_t)d * MSG + i, m);
    }
}

// ---------------------------------------------------------------------------
// Node kernel: GRU -> hnew in LDS -> coalesced output head.
// ---------------------------------------------------------------------------
__global__ __launch_bounds__(256) void node_k(
    const float* __restrict__ feat,
    const float* __restrict__ magg,
    const float* __restrict__ W_ih,
    const float* __restrict__ W_hh,
    const float* __restrict__ b_ih,
    const float* __restrict__ b_hh,
    const float* __restrict__ W_out,
    const float* __restrict__ b_out,
    float* __restrict__ out)
{
    __shared__ float hn_s[256 * 20];
    __shared__ float Wo_s[NCLS * 17];
    __shared__ float bo_s[NCLS];

    const int t = threadIdx.x;
    for (int k = t; k < NCLS * 16; k += 256) Wo_s[(k >> 4) * 17 + (k & 15)] = W_out[k];
    if (t < NCLS) bo_s[t] = b_out[t];

    const int n = blockIdx.x * 256 + t;
    if (n < NNODES) {
        float hv[HID], mv[MSG];
        const float4* hp = (const float4*)(feat + (size_t)n * HID);
        const float4* mp = (const float4*)(magg + (size_t)n * MSG);
        #pragma unroll
        for (int q = 0; q < 4; q++) {
            float4 a = hp[q];
            hv[4*q+0] = a.x; hv[4*q+1] = a.y; hv[4*q+2] = a.z; hv[4*q+3] = a.w;
            float4 c = mp[q];
            mv[4*q+0] = c.x; mv[4*q+1] = c.y; mv[4*q+2] = c.z; mv[4*q+3] = c.w;
        }
        #pragma unroll
        for (int i = 0; i < HID; i++) {
            float xr = b_ih[i], xz = b_ih[16 + i], xn = b_ih[32 + i];
            float hr = b_hh[i], hz = b_hh[16 + i], hn = b_hh[32 + i];
            #pragma unroll
            for (int j = 0; j < HID; j++) {
                xr += W_ih[(i)      * 16 + j] * mv[j];
                xz += W_ih[(16 + i) * 16 + j] * mv[j];
                xn += W_ih[(32 + i) * 16 + j] * mv[j];
                hr += W_hh[(i)      * 16 + j] * hv[j];
                hz += W_hh[(16 + i) * 16 + j] * hv[j];
                hn += W_hh[(32 + i) * 16 + j] * hv[j];
            }
            float r  = sigmoid_f(xr + hr);
            float z  = sigmoid_f(xz + hz);
            float nn = tanh_f(xn + r * hn);
            hn_s[t * 20 + i] = (1.0f - z) * nn + z * hv[i];
        }
    }
    __syncthreads();

    const int c = t & 63;
    float wr[16];
    #pragma unroll
    for (int j = 0; j < 16; j++) wr[j] = Wo_s[c * 17 + j];
    const float bo = bo_s[c];
    const int nb = blockIdx.x * 256;

    #pragma unroll 4
    for (int it = 0; it < 64; it++) {
        int k = t + 256 * it;
        int ln = k >> 6;
        int n2 = nb + ln;
        if (n2 < NNODES) {
            const float4* hq = (const float4*)(hn_s + ln * 20);
            float4 h0 = hq[0], h1 = hq[1], h2 = hq[2], h3 = hq[3];
            float a = bo;
            a += wr[0]*h0.x + wr[1]*h0.y + wr[2]*h0.z + wr[3]*h0.w;
            a += wr[4]*h1.x + wr[5]*h1.y + wr[6]*h1.z + wr[7]*h1.w;
            a += wr[8]*h2.x + wr[9]*h2.y + wr[10]*h2.z + wr[11]*h2.w;
            a += wr[12]*h3.x + wr[13]*h3.y + wr[14]*h3.z + wr[15]*h3.w;
            out[(size_t)n2 * NCLS + c] = a;
        }
    }
}

extern "C" void kernel_launch(void* const* d_in, const int* in_sizes, int n_in,
                              void* d_out, int out_size, void* d_ws, size_t ws_size,
                              hipStream_t stream) {
    const float* feat     = (const float*)d_in[0];
    const int*   src      = (const int*)d_in[1];
    const int*   dst      = (const int*)d_in[2];
    const int*   etype    = (const int*)d_in[3];
    const float* edge_emb = (const float*)d_in[4];
    const float* W_ih     = (const float*)d_in[5];
    const float* W_hh     = (const float*)d_in[6];
    const float* b_ih     = (const float*)d_in[7];
    const float* b_hh     = (const float*)d_in[8];
    const float* W_out    = (const float*)d_in[9];
    const float* b_out    = (const float*)d_in[10];
    float* out = (float*)d_out;

    // workspace layout (4-byte elements): 13.4 MB total
    float* magg   = (float*)d_ws;                         // NNODES*16
    int*   offmat = (int*)d_ws + (size_t)NNODES * MSG;    // M_SCAN
    int*   bsum   = offmat + M_SCAN;                      // NSB (pad 256)
    int*   rec    = bsum + 256;                           // NEDGES
    size_t need   = ((size_t)NNODES * MSG + M_SCAN + 256 + NEDGES) * 4;

    if (ws_size >= need) {
        hist_k    <<<NCH, 1024, 0, stream>>>(dst, offmat);
        scan_bsum <<<NSB, 256, 0, stream>>>(offmat, bsum);
        scan_top  <<<1, 256, 0, stream>>>(bsum);
        scan_write<<<NSB, 256, 0, stream>>>(bsum, offmat);
        scatter_k <<<NCH, 1024, 0, stream>>>(src, dst, etype, offmat, rec);
        agg_k     <<<NBK, 512, 0, stream>>>(feat, offmat, rec, edge_emb, magg);
    } else {
        hipMemsetAsync(magg, 0, (size_t)NNODES * MSG * sizeof(float), stream);
        ggnn_edge<<<2560, 256, 0, stream>>>(feat, src, dst, etype, edge_emb, magg);
    }
    node_k<<<(NNODES + 255) / 256, 256, 0, stream>>>(
        feat, magg, W_ih, W_hh, b_ih, b_hh, W_out, b_out, out);
}

// Round 7
// 158.731 us; speedup vs baseline: 1.7498x; 1.7498x over previous
//
#include <hip/hip_runtime.h>

#define NNODES 100000
#define NEDGES 1600000
#define HID 16
#define MSG 16
#define NTYPE 16
#define NCLS 64

#define BSH 7
#define NBK ((NNODES + 127) >> 7)           // 782 buckets of 128 nodes (dst>>7)
#define CHSZ 8192
#define NCH ((NEDGES + CHSZ - 1) / CHSZ)    // 196 edge chunks
#define M_SCAN (NBK * NCH)                  // 153,272
#define SCH 1024
#define NSB ((M_SCAN + SCH - 1) / SCH)      // 150

// At2 layout: [ty][i][h], row stride 20 floats -> quad (5i+q)&7 uniform banks
#define ASTR 20
#define ATY  320

#define RECCAP 2560     // per-bucket segment cap for in-LDS sort
#define CHUNK 16        // edges per 16-lane group in agg2
#define NCHK ((NEDGES + CHUNK - 1) / CHUNK)   // 100,000 chunks
#define AGG2_BLOCKS ((NCHK + 15) / 16)        // 6,250 blocks

__device__ __forceinline__ float sigmoid_f(float x) {
    return 1.0f / (1.0f + __expf(-x));
}
__device__ __forceinline__ float tanh_f(float x) {
    x = fminf(fmaxf(x, -15.0f), 15.0f);
    float e = __expf(2.0f * x);
    return (e - 1.0f) / (e + 1.0f);
}

// ---------------------------------------------------------------------------
// Phase A: per-chunk bucket histogram (LDS atomics only)
// ---------------------------------------------------------------------------
__global__ __launch_bounds__(1024) void hist_k(const int* __restrict__ dst,
                                               int* __restrict__ cntmat) {
    __shared__ int cnt[NBK];
    const int t = threadIdx.x, ch = blockIdx.x;
    for (int b = t; b < NBK; b += 1024) cnt[b] = 0;
    __syncthreads();
    #pragma unroll
    for (int k = 0; k < CHSZ / 1024; k++) {
        int e = ch * CHSZ + k * 1024 + t;
        if (e < NEDGES) atomicAdd(&cnt[dst[e] >> BSH], 1);
    }
    __syncthreads();
    for (int b = t; b < NBK; b += 1024) cntmat[b * NCH + ch] = cnt[b];
}

// ---------------------------------------------------------------------------
// Phase B: exclusive scan of cntmat (bucket-major), in place. 3 kernels.
// ---------------------------------------------------------------------------
__global__ __launch_bounds__(256) void scan_bsum(const int* __restrict__ x,
                                                 int* __restrict__ bsum) {
    const int t = threadIdx.x;
    int base = blockIdx.x * SCH + t * 4;
    int s = 0;
    #pragma unroll
    for (int q = 0; q < 4; q++) {
        int idx = base + q;
        if (idx < M_SCAN) s += x[idx];
    }
    #pragma unroll
    for (int d = 32; d > 0; d >>= 1) s += __shfl_down(s, d, 64);
    __shared__ int ws[4];
    int lane = t & 63, w = t >> 6;
    if (lane == 0) ws[w] = s;
    __syncthreads();
    if (t == 0) bsum[blockIdx.x] = ws[0] + ws[1] + ws[2] + ws[3];
}

__global__ __launch_bounds__(256) void scan_top(int* __restrict__ bsum) {
    const int t = threadIdx.x;
    int v = (t < NSB) ? bsum[t] : 0;
    int lane = t & 63, w = t >> 6;
    int s = v;
    #pragma unroll
    for (int d = 1; d < 64; d <<= 1) {
        int u = __shfl_up(s, d, 64);
        if (lane >= d) s += u;
    }
    __shared__ int ws[4];
    if (lane == 63) ws[w] = s;
    __syncthreads();
    int base = 0;
    #pragma unroll
    for (int q = 0; q < 4; q++) if (q < w) base += ws[q];
    if (t < NSB) bsum[t] = base + s - v;
}

__global__ __launch_bounds__(256) void scan_write(const int* __restrict__ bsum,
                                                  int* __restrict__ x) {
    const int t = threadIdx.x;
    int base = blockIdx.x * SCH + t * 4;
    int v[4]; int ts = 0;
    #pragma unroll
    for (int q = 0; q < 4; q++) {
        int idx = base + q;
        v[q] = (idx < M_SCAN) ? x[idx] : 0;
        ts += v[q];
    }
    int lane = t & 63, w = t >> 6;
    int s = ts;
    #pragma unroll
    for (int d = 1; d < 64; d <<= 1) {
        int u = __shfl_up(s, d, 64);
        if (lane >= d) s += u;
    }
    __shared__ int ws[4];
    if (lane == 63) ws[w] = s;
    __syncthreads();
    int wbase = 0;
    #pragma unroll
    for (int q = 0; q < 4; q++) if (q < w) wbase += ws[q];
    int run = bsum[blockIdx.x] + wbase + (s - ts);
    #pragma unroll
    for (int q = 0; q < 4; q++) {
        int idx = base + q;
        if (idx < M_SCAN) x[idx] = run;
        run += v[q];
    }
}

// ---------------------------------------------------------------------------
// Phase C: scatter into bucket-grouped records. rec = src | et<<17 | (dst&127)<<21
// ---------------------------------------------------------------------------
__global__ __launch_bounds__(1024) void scatter_k(const int* __restrict__ src,
                                                  const int* __restrict__ dst,
                                                  const int* __restrict__ et,
                                                  const int* __restrict__ offmat,
                                                  int* __restrict__ rec) {
    __shared__ int offc[NBK];
    const int t = threadIdx.x, ch = blockIdx.x;
    for (int b = t; b < NBK; b += 1024) offc[b] = offmat[b * NCH + ch];
    __syncthreads();
    #pragma unroll
    for (int k = 0; k < CHSZ / 1024; k++) {
        int e = ch * CHSZ + k * 1024 + t;
        if (e < NEDGES) {
            int d = dst[e];
            int b = d >> BSH;
            int pos = atomicAdd(&offc[b], 1);
            rec[pos] = src[e] | (et[e] << 17) | ((d & 127) << 21);
        }
    }
}

// ---------------------------------------------------------------------------
// Phase C2: bucket boundary extraction: bnd[b] = segment start, bnd[NBK]=NEDGES
// ---------------------------------------------------------------------------
__global__ __launch_bounds__(256) void bnd_k(const int* __restrict__ offmat,
                                             int* __restrict__ bnd) {
    int k = blockIdx.x * 256 + threadIdx.x;
    if (k < NBK) bnd[k] = offmat[k * NCH];
    if (k == NBK) bnd[k] = NEDGES;
}

// ---------------------------------------------------------------------------
// Phase C3: in-LDS counting sort of each bucket segment by dst&127 ->
// rec becomes FULLY dst-sorted (runs avg 16, enabling run compression).
// Order within equal dst is irrelevant.
// ---------------------------------------------------------------------------
__global__ __launch_bounds__(256) void sort2_k(const int* __restrict__ offmat,
                                               int* __restrict__ rec) {
    __shared__ int buf[RECCAP];
    __shared__ int cnt[128];
    __shared__ int basec[128];
    __shared__ int wtot[4];
    const int t = threadIdx.x, b = blockIdx.x;
    const int jb = offmat[b * NCH];
    const int je = (b == NBK - 1) ? NEDGES : offmat[(b + 1) * NCH];
    const int len = je - jb;
    if (len <= 0 || len > RECCAP) return;   // uniform branch; unsorted = still correct

    if (t < 128) cnt[t] = 0;
    for (int k = t; k < len; k += 256) buf[k] = rec[jb + k];
    __syncthreads();
    for (int k = t; k < len; k += 256) atomicAdd(&cnt[((unsigned)buf[k]) >> 21], 1);
    __syncthreads();
    int v = (t < 128) ? cnt[t] : 0;
    int lane = t & 63, w = t >> 6;
    int s = v;
    #pragma unroll
    for (int d = 1; d < 64; d <<= 1) {
        int u = __shfl_up(s, d, 64);
        if (lane >= d) s += u;
    }
    if (lane == 63) wtot[w] = s;
    __syncthreads();
    if (t < 128) basec[t] = s - v + (w == 1 ? wtot[0] : 0);
    __syncthreads();
    for (int k = t; k < len; k += 256) {
        int r = buf[k];
        int p = atomicAdd(&basec[((unsigned)r) >> 21], 1);
        rec[jb + p] = r;
    }
}

// ---------------------------------------------------------------------------
// Phase D: FLAT aggregation over sorted rec. 6250 blocks x 256 threads;
// each 16-lane group owns one 16-edge chunk (serial depth 16, huge TLP).
// Pairs of feat gathers issued before use (sched_barrier fence); register
// run-compression -> atomic flush only on dst change (~194K flushes).
// ---------------------------------------------------------------------------
__device__ __forceinline__ float dot16(const float4* A, float4 f0, float4 f1,
                                       float4 f2, float4 f3) {
    float4 A0 = A[0], A1 = A[1], A2 = A[2], A3 = A[3];
    float m;
    m  = A0.x*f0.x + A0.y*f0.y + A0.z*f0.z + A0.w*f0.w;
    m += A1.x*f1.x + A1.y*f1.y + A1.z*f1.z + A1.w*f1.w;
    m += A2.x*f2.x + A2.y*f2.y + A2.z*f2.z + A2.w*f2.w;
    m += A3.x*f3.x + A3.y*f3.y + A3.z*f3.z + A3.w*f3.w;
    return m;
}

__global__ __launch_bounds__(256) void agg2_k(const float* __restrict__ feat,
                                              const int* __restrict__ rec,
                                              const int* __restrict__ bnd_g,
                                              const float* __restrict__ edge_emb,
                                              float* __restrict__ magg) {
    __shared__ float At2[NTYPE * ATY];   // 20.5 KB
    __shared__ int bnd[NBK + 1];         // 3.1 KB
    const int t = threadIdx.x;
    #pragma unroll
    for (int idx = t; idx < NTYPE * MSG * HID; idx += 256) {
        int ty = idx >> 8, rem = idx & 255, ii = rem >> 4, h = rem & 15;
        At2[ty * ATY + ii * ASTR + h] = edge_emb[idx];
    }
    for (int k = t; k < NBK + 1; k += 256) bnd[k] = bnd_g[k];
    __syncthreads();

    const int g = t >> 4, i = t & 15;
    const int chunk = blockIdx.x * 16 + g;
    if (chunk >= NCHK) return;
    const int j0 = chunk * CHUNK;
    const int jend = (j0 + CHUNK < NEDGES) ? j0 + CHUNK : NEDGES;

    // binary search: bucket containing j0
    int lo = 0, hi = NBK;
    while (hi - lo > 1) {
        int mid = (lo + hi) >> 1;
        if (bnd[mid] <= j0) lo = mid; else hi = mid;
    }
    int b = lo, bnext = bnd[b + 1];

    float macc = 0.0f;
    int cur = -1;
    int j = j0;
    while (j < jend) {
        const bool has2 = (j + 1 < jend);
        int r1 = rec[j];
        int r2 = has2 ? rec[j + 1] : r1;
        const float4* p1 = (const float4*)(feat + (size_t)(r1 & 0x1FFFF) * HID);
        const float4* p2 = (const float4*)(feat + (size_t)(r2 & 0x1FFFF) * HID);
        float4 Fa0 = p1[0], Fa1 = p1[1], Fa2 = p1[2], Fa3 = p1[3];
        float4 Fb0 = p2[0], Fb1 = p2[1], Fb2 = p2[2], Fb3 = p2[3];
        __builtin_amdgcn_sched_barrier(0);   // keep both gathers issued up here

        while (j >= bnext) { ++b; bnext = bnd[b + 1]; }
        {
            int d1  = (b << BSH) | (((unsigned)r1) >> 21);
            int ty1 = (r1 >> 17) & 15;
            float m1 = dot16((const float4*)(At2 + ty1 * ATY + i * ASTR),
                             Fa0, Fa1, Fa2, Fa3);
            if (d1 != cur) {
                if (cur >= 0) atomicAdd(&magg[(size_t)cur * MSG + i], macc);
                macc = 0.0f; cur = d1;
            }
            macc += m1;
        }
        if (has2) {
            while (j + 1 >= bnext) { ++b; bnext = bnd[b + 1]; }
            int d2  = (b << BSH) | (((unsigned)r2) >> 21);
            int ty2 = (r2 >> 17) & 15;
            float m2 = dot16((const float4*)(At2 + ty2 * ATY + i * ASTR),
                             Fb0, Fb1, Fb2, Fb3);
            if (d2 != cur) {
                atomicAdd(&magg[(size_t)cur * MSG + i], macc);
                macc = 0.0f; cur = d2;
            }
            macc += m2;
        }
        j += 2;
    }
    if (cur >= 0) atomicAdd(&magg[(size_t)cur * MSG + i], macc);
}

// ---------------------------------------------------------------------------
// Fallback atomic edge kernel (only if ws too small)
// ---------------------------------------------------------------------------
__global__ __launch_bounds__(256) void ggnn_edge(
    const float* __restrict__ feat,
    const int* __restrict__ src,
    const int* __restrict__ dst,
    const int* __restrict__ etype,
    const float* __restrict__ edge_emb,
    float* __restrict__ magg)
{
    __shared__ float At[NTYPE * MSG * HID];
    for (int idx = threadIdx.x; idx < NTYPE * MSG * HID; idx += 256) {
        int ty = idx >> 8, rem = idx & 255, i = rem >> 4, hh = rem & 15;
        At[(ty << 8) | (hh << 4) | i] = edge_emb[idx];
    }
    __syncthreads();
    const long long total = (long long)NEDGES * MSG;
    for (long long w = (long long)blockIdx.x * 256 + threadIdx.x; w < total;
         w += (long long)gridDim.x * 256) {
        const int e = (int)(w >> 4);
        const int i = (int)(w & 15);
        const int s = src[e];
        const int d = dst[e];
        const int ty = etype[e];
        const float4* fp = (const float4*)(feat + (size_t)s * HID);
        const float4 f0 = fp[0], f1 = fp[1], f2 = fp[2], f3 = fp[3];
        const float* a = At + (ty << 8) + i;
        float m;
        m  = a[0*16]*f0.x + a[1*16]*f0.y + a[2*16]*f0.z + a[3*16]*f0.w;
        m += a[4*16]*f1.x + a[5*16]*f1.y + a[6*16]*f1.z + a[7*16]*f1.w;
        m += a[8*16]*f2.x + a[9*16]*f2.y + a[10*16]*f2.z + a[11*16]*f2.w;
        m += a[12*16]*f3.x + a[13*16]*f3.y + a[14*16]*f3.z + a[15*16]*f3.w;
        atomicAdd(magg + (size_t)d * MSG + i, m);
    }
}

// ---------------------------------------------------------------------------
// Node kernel: GRU -> hnew in LDS -> output head with float4 stores
// (lane owns 4 consecutive classes; W_out rows in registers).
// ---------------------------------------------------------------------------
__global__ __launch_bounds__(256) void node_k(
    const float* __restrict__ feat,
    const float* __restrict__ magg,
    const float* __restrict__ W_ih,
    const float* __restrict__ W_hh,
    const float* __restrict__ b_ih,
    const float* __restrict__ b_hh,
    const float* __restrict__ W_out,
    const float* __restrict__ b_out,
    float* __restrict__ out)
{
    __shared__ float hn_s[256 * 20];
    const int t = threadIdx.x;
    const int n = blockIdx.x * 256 + t;
    if (n < NNODES) {
        float hv[HID], mv[MSG];
        const float4* hp = (const float4*)(feat + (size_t)n * HID);
        const float4* mp = (const float4*)(magg + (size_t)n * MSG);
        #pragma unroll
        for (int q = 0; q < 4; q++) {
            float4 a = hp[q];
            hv[4*q+0] = a.x; hv[4*q+1] = a.y; hv[4*q+2] = a.z; hv[4*q+3] = a.w;
            float4 c = mp[q];
            mv[4*q+0] = c.x; mv[4*q+1] = c.y; mv[4*q+2] = c.z; mv[4*q+3] = c.w;
        }
        #pragma unroll
        for (int i = 0; i < HID; i++) {
            float xr = b_ih[i], xz = b_ih[16 + i], xn = b_ih[32 + i];
            float hr = b_hh[i], hz = b_hh[16 + i], hn = b_hh[32 + i];
            #pragma unroll
            for (int j = 0; j < HID; j++) {
                xr += W_ih[(i)      * 16 + j] * mv[j];
                xz += W_ih[(16 + i) * 16 + j] * mv[j];
                xn += W_ih[(32 + i) * 16 + j] * mv[j];
                hr += W_hh[(i)      * 16 + j] * hv[j];
                hz += W_hh[(16 + i) * 16 + j] * hv[j];
                hn += W_hh[(32 + i) * 16 + j] * hv[j];
            }
            float r  = sigmoid_f(xr + hr);
            float z  = sigmoid_f(xz + hz);
            float nn = tanh_f(xn + r * hn);
            hn_s[t * 20 + i] = (1.0f - z) * nn + z * hv[i];
        }
    }
    __syncthreads();

    // Output phase: lane li covers classes [4*li, 4*li+4) of one node.
    const int w = t >> 6, g = (t >> 4) & 3, li = t & 15;
    float4 w4[4][4];
    #pragma unroll
    for (int rr = 0; rr < 4; rr++)
        #pragma unroll
        for (int qq = 0; qq < 4; qq++)
            w4[rr][qq] = ((const float4*)W_out)[(4 * li + rr) * 4 + qq];
    const float4 bo4 = ((const float4*)b_out)[li];
    const int nb = blockIdx.x * 256;

    #pragma unroll
    for (int it = 0; it < 16; it++) {
        int ln = it * 16 + w * 4 + g;
        int n2 = nb + ln;
        if (n2 < NNODES) {
            const float4* hq = (const float4*)(hn_s + ln * 20);
            float4 h0 = hq[0], h1 = hq[1], h2 = hq[2], h3 = hq[3];
            float4 o;
            o.x = bo4.x + w4[0][0].x*h0.x + w4[0][0].y*h0.y + w4[0][0].z*h0.z + w4[0][0].w*h0.w
                        + w4[0][1].x*h1.x + w4[0][1].y*h1.y + w4[0][1].z*h1.z + w4[0][1].w*h1.w
                        + w4[0][2].x*h2.x + w4[0][2].y*h2.y + w4[0][2].z*h2.z + w4[0][2].w*h2.w
                        + w4[0][3].x*h3.x + w4[0][3].y*h3.y + w4[0][3].z*h3.z + w4[0][3].w*h3.w;
            o.y = bo4.y + w4[1][0].x*h0.x + w4[1][0].y*h0.y + w4[1][0].z*h0.z + w4[1][0].w*h0.w
                        + w4[1][1].x*h1.x + w4[1][1].y*h1.y + w4[1][1].z*h1.z + w4[1][1].w*h1.w
                        + w4[1][2].x*h2.x + w4[1][2].y*h2.y + w4[1][2].z*h2.z + w4[1][2].w*h2.w
                        + w4[1][3].x*h3.x + w4[1][3].y*h3.y + w4[1][3].z*h3.z + w4[1][3].w*h3.w;
            o.z = bo4.z + w4[2][0].x*h0.x + w4[2][0].y*h0.y + w4[2][0].z*h0.z + w4[2][0].w*h0.w
                        + w4[2][1].x*h1.x + w4[2][1].y*h1.y + w4[2][1].z*h1.z + w4[2][1].w*h1.w
                        + w4[2][2].x*h2.x + w4[2][2].y*h2.y + w4[2][2].z*h2.z + w4[2][2].w*h2.w
                        + w4[2][3].x*h3.x + w4[2][3].y*h3.y + w4[2][3].z*h3.z + w4[2][3].w*h3.w;
            o.w = bo4.w + w4[3][0].x*h0.x + w4[3][0].y*h0.y + w4[3][0].z*h0.z + w4[3][0].w*h0.w
                        + w4[3][1].x*h1.x + w4[3][1].y*h1.y + w4[3][1].z*h1.z + w4[3][1].w*h1.w
                        + w4[3][2].x*h2.x + w4[3][2].y*h2.y + w4[3][2].z*h2.z + w4[3][2].w*h2.w
                        + w4[3][3].x*h3.x + w4[3][3].y*h3.y + w4[3][3].z*h3.z + w4[3][3].w*h3.w;
            ((float4*)(out + (size_t)n2 * NCLS))[li] = o;
        }
    }
}

extern "C" void kernel_launch(void* const* d_in, const int* in_sizes, int n_in,
                              void* d_out, int out_size, void* d_ws, size_t ws_size,
                              hipStream_t stream) {
    const float* feat     = (const float*)d_in[0];
    const int*   src      = (const int*)d_in[1];
    const int*   dst      = (const int*)d_in[2];
    const int*   etype    = (const int*)d_in[3];
    const float* edge_emb = (const float*)d_in[4];
    const float* W_ih     = (const float*)d_in[5];
    const float* W_hh     = (const float*)d_in[6];
    const float* b_ih     = (const float*)d_in[7];
    const float* b_hh     = (const float*)d_in[8];
    const float* W_out    = (const float*)d_in[9];
    const float* b_out    = (const float*)d_in[10];
    float* out = (float*)d_out;

    // workspace layout (4-byte elements): ~13.4 MB
    float* magg   = (float*)d_ws;                         // NNODES*16
    int*   offmat = (int*)d_ws + (size_t)NNODES * MSG;    // M_SCAN
    int*   bsum   = offmat + M_SCAN;                      // 256 (NSB used)
    int*   bnd    = bsum + 256;                           // 1024 (NBK+1 used)
    int*   rec    = bnd + 1024;                           // NEDGES
    size_t need   = ((size_t)NNODES * MSG + M_SCAN + 256 + 1024 + NEDGES) * 4;

    hipMemsetAsync(magg, 0, (size_t)NNODES * MSG * sizeof(float), stream);
    if (ws_size >= need) {
        hist_k    <<<NCH, 1024, 0, stream>>>(dst, offmat);
        scan_bsum <<<NSB, 256, 0, stream>>>(offmat, bsum);
        scan_top  <<<1, 256, 0, stream>>>(bsum);
        scan_write<<<NSB, 256, 0, stream>>>(bsum, offmat);
        scatter_k <<<NCH, 1024, 0, stream>>>(src, dst, etype, offmat, rec);
        bnd_k     <<<4, 256, 0, stream>>>(offmat, bnd);
        sort2_k   <<<NBK, 256, 0, stream>>>(offmat, rec);
        agg2_k    <<<AGG2_BLOCKS, 256, 0, stream>>>(feat, rec, bnd, edge_emb, magg);
    } else {
        ggnn_edge<<<2560, 256, 0, stream>>>(feat, src, dst, etype, edge_emb, magg);
    }
    node_k<<<(NNODES + 255) / 256, 256, 0, stream>>>(
        feat, magg, W_ih, W_hh, b_ih, b_hh, W_out, b_out, out);
}

// Round 8
// 141.986 us; speedup vs baseline: 1.9561x; 1.1179x over previous
//
#include <hip/hip_runtime.h>

#define NNODES 100000
#define NEDGES 1600000
#define HID 16
#define MSG 16
#define NTYPE 16
#define NCLS 64

#define BSH 7
#define NBK ((NNODES + 127) >> 7)           // 782 buckets of 128 nodes (dst>>7)
#define CHSZ 8192
#define NCH ((NEDGES + CHSZ - 1) / CHSZ)    // 196 edge chunks
#define M_SCAN (NBK * NCH)                  // 153,272
#define SCH 1024
#define NSB ((M_SCAN + SCH - 1) / SCH)      // 150

// At2 layout: [ty][i][h], row stride 20 floats -> quad (5i+q)&7 uniform banks
#define ASTR 20
#define ATY  320

#define RECCAP 2560     // per-bucket segment cap for in-LDS sort
#define CHUNK 16        // edges per 16-lane group in agg2
#define NCHK (NEDGES / CHUNK)                 // 100,000 chunks
#define AGG2_BLOCKS (NCHK / 16)               // 6,250 blocks (exact cover)

__device__ __forceinline__ float sigmoid_f(float x) {
    return 1.0f / (1.0f + __expf(-x));
}
__device__ __forceinline__ float tanh_f(float x) {
    x = fminf(fmaxf(x, -15.0f), 15.0f);
    float e = __expf(2.0f * x);
    return (e - 1.0f) / (e + 1.0f);
}

// ---------------------------------------------------------------------------
// Phase A: per-chunk bucket histogram (LDS atomics only)
// ---------------------------------------------------------------------------
__global__ __launch_bounds__(1024) void hist_k(const int* __restrict__ dst,
                                               int* __restrict__ cntmat) {
    __shared__ int cnt[NBK];
    const int t = threadIdx.x, ch = blockIdx.x;
    for (int b = t; b < NBK; b += 1024) cnt[b] = 0;
    __syncthreads();
    #pragma unroll
    for (int k = 0; k < CHSZ / 1024; k++) {
        int e = ch * CHSZ + k * 1024 + t;
        if (e < NEDGES) atomicAdd(&cnt[dst[e] >> BSH], 1);
    }
    __syncthreads();
    for (int b = t; b < NBK; b += 1024) cntmat[b * NCH + ch] = cnt[b];
}

// ---------------------------------------------------------------------------
// Phase B1: per-scan-block sums
// ---------------------------------------------------------------------------
__global__ __launch_bounds__(256) void scan_bsum(const int* __restrict__ x,
                                                 int* __restrict__ bsum) {
    const int t = threadIdx.x;
    int base = blockIdx.x * SCH + t * 4;
    int s = 0;
    #pragma unroll
    for (int q = 0; q < 4; q++) {
        int idx = base + q;
        if (idx < M_SCAN) s += x[idx];
    }
    #pragma unroll
    for (int d = 32; d > 0; d >>= 1) s += __shfl_down(s, d, 64);
    __shared__ int ws[4];
    int lane = t & 63, w = t >> 6;
    if (lane == 0) ws[w] = s;
    __syncthreads();
    if (t == 0) bsum[blockIdx.x] = ws[0] + ws[1] + ws[2] + ws[3];
}

// ---------------------------------------------------------------------------
// Phase B2 (fused top+write): each block recomputes its global prefix from
// bsum (NSB<=256), scans its chunk in place, and emits bnd[] boundaries.
// ---------------------------------------------------------------------------
__global__ __launch_bounds__(256) void scan_write(const int* __restrict__ bsum,
                                                  int* __restrict__ x,
                                                  int* __restrict__ bnd) {
    const int t = threadIdx.x;
    __shared__ int wsA[4];
    __shared__ int bpref_s;
    {
        int v = (t < blockIdx.x && t < NSB) ? bsum[t] : 0;
        #pragma unroll
        for (int d = 32; d > 0; d >>= 1) v += __shfl_down(v, d, 64);
        int lane = t & 63, w = t >> 6;
        if (lane == 0) wsA[w] = v;
        __syncthreads();
        if (t == 0) bpref_s = wsA[0] + wsA[1] + wsA[2] + wsA[3];
        __syncthreads();
    }

    int base = blockIdx.x * SCH + t * 4;
    int v[4]; int ts = 0;
    #pragma unroll
    for (int q = 0; q < 4; q++) {
        int idx = base + q;
        v[q] = (idx < M_SCAN) ? x[idx] : 0;
        ts += v[q];
    }
    int lane = t & 63, w = t >> 6;
    int s = ts;
    #pragma unroll
    for (int d = 1; d < 64; d <<= 1) {
        int u = __shfl_up(s, d, 64);
        if (lane >= d) s += u;
    }
    __shared__ int wsB[4];
    if (lane == 63) wsB[w] = s;
    __syncthreads();
    int wbase = 0;
    #pragma unroll
    for (int q = 0; q < 4; q++) if (q < w) wbase += wsB[q];
    int run = bpref_s + wbase + (s - ts);
    #pragma unroll
    for (int q = 0; q < 4; q++) {
        int idx = base + q;
        if (idx < M_SCAN) {
            x[idx] = run;
            if (idx % NCH == 0) bnd[idx / NCH] = run;   // bucket boundary
        }
        run += v[q];
    }
    if (blockIdx.x == 0 && t == 0) bnd[NBK] = NEDGES;
}

// ---------------------------------------------------------------------------
// Phase C: scatter into bucket-grouped records. rec = src | et<<17 | (dst&127)<<21
// ---------------------------------------------------------------------------
__global__ __launch_bounds__(1024) void scatter_k(const int* __restrict__ src,
                                                  const int* __restrict__ dst,
                                                  const int* __restrict__ et,
                                                  const int* __restrict__ offmat,
                                                  int* __restrict__ rec) {
    __shared__ int offc[NBK];
    const int t = threadIdx.x, ch = blockIdx.x;
    for (int b = t; b < NBK; b += 1024) offc[b] = offmat[b * NCH + ch];
    __syncthreads();
    #pragma unroll
    for (int k = 0; k < CHSZ / 1024; k++) {
        int e = ch * CHSZ + k * 1024 + t;
        if (e < NEDGES) {
            int d = dst[e];
            int b = d >> BSH;
            int pos = atomicAdd(&offc[b], 1);
            rec[pos] = src[e] | (et[e] << 17) | ((d & 127) << 21);
        }
    }
}

// ---------------------------------------------------------------------------
// Phase C2: in-LDS counting sort of each bucket segment by dst&127 (-> rec
// fully dst-sorted), and cb[] chunk->start-bucket table (written ALWAYS,
// even for oversized/unsorted buckets, to keep agg2 correct).
// ---------------------------------------------------------------------------
__global__ __launch_bounds__(256) void sort2_k(const int* __restrict__ bnd,
                                               int* __restrict__ rec,
                                               int* __restrict__ cb) {
    __shared__ int buf[RECCAP];
    __shared__ int cnt[128];
    __shared__ int basec[128];
    __shared__ int wtot[4];
    const int t = threadIdx.x, b = blockIdx.x;
    const int jb = bnd[b];
    const int je = bnd[b + 1];
    const int len = je - jb;

    if (len > 0 && len <= RECCAP) {
        if (t < 128) cnt[t] = 0;
        for (int k = t; k < len; k += 256) buf[k] = rec[jb + k];
        __syncthreads();
        for (int k = t; k < len; k += 256) atomicAdd(&cnt[((unsigned)buf[k]) >> 21], 1);
        __syncthreads();
        int v = (t < 128) ? cnt[t] : 0;
        int lane = t & 63, w = t >> 6;
        int s = v;
        #pragma unroll
        for (int d = 1; d < 64; d <<= 1) {
            int u = __shfl_up(s, d, 64);
            if (lane >= d) s += u;
        }
        if (lane == 63) wtot[w] = s;
        __syncthreads();
        if (t < 128) basec[t] = s - v + (w == 1 ? wtot[0] : 0);
        __syncthreads();
        for (int k = t; k < len; k += 256) {
            int r = buf[k];
            int p = atomicAdd(&basec[((unsigned)r) >> 21], 1);
            rec[jb + p] = r;
        }
    }

    // cb: chunks whose start edge lies in [jb, je)
    const int c0 = (jb + CHUNK - 1) >> 4;
    const int c1 = (je + CHUNK - 1) >> 4;
    for (int c = c0 + t; c < c1; c += 256) cb[c] = b;
}

// ---------------------------------------------------------------------------
// Phase D: FLAT aggregation over sorted rec. 6250 blocks x 256 threads;
// 16-lane group owns one 16-edge chunk. Records LDS-staged (coalesced),
// bucket via precomputed cb[] + L1-hot bnd walk; fixed 8-pair loop with
// pre-issued feat gathers; register run-compression.
// ---------------------------------------------------------------------------
__device__ __forceinline__ float dot16(const float4* A, float4 f0, float4 f1,
                                       float4 f2, float4 f3) {
    float4 A0 = A[0], A1 = A[1], A2 = A[2], A3 = A[3];
    float m;
    m  = A0.x*f0.x + A0.y*f0.y + A0.z*f0.z + A0.w*f0.w;
    m += A1.x*f1.x + A1.y*f1.y + A1.z*f1.z + A1.w*f1.w;
    m += A2.x*f2.x + A2.y*f2.y + A2.z*f2.z + A2.w*f2.w;
    m += A3.x*f3.x + A3.y*f3.y + A3.z*f3.z + A3.w*f3.w;
    return m;
}

__global__ __launch_bounds__(256) void agg2_k(const float* __restrict__ feat,
                                              const int* __restrict__ rec,
                                              const int* __restrict__ bnd,
                                              const int* __restrict__ cb,
                                              const float* __restrict__ edge_emb,
                                              float* __restrict__ magg) {
    __shared__ float At2[NTYPE * ATY];   // 20.5 KB
    __shared__ int recs[256];            // 1 KB
    const int t = threadIdx.x;
    #pragma unroll
    for (int idx = t; idx < NTYPE * MSG * HID; idx += 256) {
        int ty = idx >> 8, rem = idx & 255, ii = rem >> 4, h = rem & 15;
        At2[ty * ATY + ii * ASTR + h] = edge_emb[idx];
    }
    recs[t] = rec[blockIdx.x * 256 + t];   // grid covers NEDGES exactly
    __syncthreads();

    const int g = t >> 4, i = t & 15;
    const int chunk = blockIdx.x * 16 + g;
    const int jbase = chunk << 4;
    const int lbase = g << 4;

    int b = cb[chunk];
    int bnext = bnd[b + 1];

    float macc = 0.0f;
    int cur = -1;
    #pragma unroll 1
    for (int p = 0; p < 8; p++) {
        int r1 = recs[lbase + 2 * p];
        int r2 = recs[lbase + 2 * p + 1];
        const float4* p1 = (const float4*)(feat + (size_t)(r1 & 0x1FFFF) * HID);
        const float4* p2 = (const float4*)(feat + (size_t)(r2 & 0x1FFFF) * HID);
        float4 Fa0 = p1[0], Fa1 = p1[1], Fa2 = p1[2], Fa3 = p1[3];
        float4 Fb0 = p2[0], Fb1 = p2[1], Fb2 = p2[2], Fb3 = p2[3];
        __builtin_amdgcn_sched_barrier(0);   // keep both gathers issued above

        int j = jbase + 2 * p;
        while (j >= bnext) { ++b; bnext = bnd[b + 1]; }
        int d1 = (b << BSH) | (((unsigned)r1) >> 21);
        float m1 = dot16((const float4*)(At2 + ((r1 >> 17) & 15) * ATY + i * ASTR),
                         Fa0, Fa1, Fa2, Fa3);
        if (d1 != cur) {
            if (cur >= 0) atomicAdd(&magg[(size_t)cur * MSG + i], macc);
            macc = 0.0f; cur = d1;
        }
        macc += m1;

        while (j + 1 >= bnext) { ++b; bnext = bnd[b + 1]; }
        int d2 = (b << BSH) | (((unsigned)r2) >> 21);
        float m2 = dot16((const float4*)(At2 + ((r2 >> 17) & 15) * ATY + i * ASTR),
                         Fb0, Fb1, Fb2, Fb3);
        if (d2 != cur) {
            atomicAdd(&magg[(size_t)cur * MSG + i], macc);
            macc = 0.0f; cur = d2;
        }
        macc += m2;
    }
    atomicAdd(&magg[(size_t)cur * MSG + i], macc);
}

// ---------------------------------------------------------------------------
// Fallback atomic edge kernel (only if ws too small)
// ---------------------------------------------------------------------------
__global__ __launch_bounds__(256) void ggnn_edge(
    const float* __restrict__ feat,
    const int* __restrict__ src,
    const int* __restrict__ dst,
    const int* __restrict__ etype,
    const float* __restrict__ edge_emb,
    float* __restrict__ magg)
{
    __shared__ float At[NTYPE * MSG * HID];
    for (int idx = threadIdx.x; idx < NTYPE * MSG * HID; idx += 256) {
        int ty = idx >> 8, rem = idx & 255, i = rem >> 4, hh = rem & 15;
        At[(ty << 8) | (hh << 4) | i] = edge_emb[idx];
    }
    __syncthreads();
    const long long total = (long long)NEDGES * MSG;
    for (long long w = (long long)blockIdx.x * 256 + threadIdx.x; w < total;
         w += (long long)gridDim.x * 256) {
        const int e = (int)(w >> 4);
        const int i = (int)(w & 15);
        const int s = src[e];
        const int d = dst[e];
        const int ty = etype[e];
        const float4* fp = (const float4*)(feat + (size_t)s * HID);
        const float4 f0 = fp[0], f1 = fp[1], f2 = fp[2], f3 = fp[3];
        const float* a = At + (ty << 8) + i;
        float m;
        m  = a[0*16]*f0.x + a[1*16]*f0.y + a[2*16]*f0.z + a[3*16]*f0.w;
        m += a[4*16]*f1.x + a[5*16]*f1.y + a[6*16]*f1.z + a[7*16]*f1.w;
        m += a[8*16]*f2.x + a[9*16]*f2.y + a[10*16]*f2.z + a[11*16]*f2.w;
        m += a[12*16]*f3.x + a[13*16]*f3.y + a[14*16]*f3.z + a[15*16]*f3.w;
        atomicAdd(magg + (size_t)d * MSG + i, m);
    }
}

// ---------------------------------------------------------------------------
// Node kernel: GRU -> hnew in LDS -> output head with float4 stores.
// ---------------------------------------------------------------------------
__global__ __launch_bounds__(256) void node_k(
    const float* __restrict__ feat,
    const float* __restrict__ magg,
    const float* __restrict__ W_ih,
    const float* __restrict__ W_hh,
    const float* __restrict__ b_ih,
    const float* __restrict__ b_hh,
    const float* __restrict__ W_out,
    const float* __restrict__ b_out,
    float* __restrict__ out)
{
    __shared__ float hn_s[256 * 20];
    const int t = threadIdx.x;
    const int n = blockIdx.x * 256 + t;
    if (n < NNODES) {
        float hv[HID], mv[MSG];
        const float4* hp = (const float4*)(feat + (size_t)n * HID);
        const float4* mp = (const float4*)(magg + (size_t)n * MSG);
        #pragma unroll
        for (int q = 0; q < 4; q++) {
            float4 a = hp[q];
            hv[4*q+0] = a.x; hv[4*q+1] = a.y; hv[4*q+2] = a.z; hv[4*q+3] = a.w;
            float4 c = mp[q];
            mv[4*q+0] = c.x; mv[4*q+1] = c.y; mv[4*q+2] = c.z; mv[4*q+3] = c.w;
        }
        #pragma unroll
        for (int i = 0; i < HID; i++) {
            float xr = b_ih[i], xz = b_ih[16 + i], xn = b_ih[32 + i];
            float hr = b_hh[i], hz = b_hh[16 + i], hn = b_hh[32 + i];
            #pragma unroll
            for (int j = 0; j < HID; j++) {
                xr += W_ih[(i)      * 16 + j] * mv[j];
                xz += W_ih[(16 + i) * 16 + j] * mv[j];
                xn += W_ih[(32 + i) * 16 + j] * mv[j];
                hr += W_hh[(i)      * 16 + j] * hv[j];
                hz += W_hh[(16 + i) * 16 + j] * hv[j];
                hn += W_hh[(32 + i) * 16 + j] * hv[j];
            }
            float r  = sigmoid_f(xr + hr);
            float z  = sigmoid_f(xz + hz);
            float nn = tanh_f(xn + r * hn);
            hn_s[t * 20 + i] = (1.0f - z) * nn + z * hv[i];
        }
    }
    __syncthreads();

    const int w = t >> 6, g = (t >> 4) & 3, li = t & 15;
    float4 w4[4][4];
    #pragma unroll
    for (int rr = 0; rr < 4; rr++)
        #pragma unroll
        for (int qq = 0; qq < 4; qq++)
            w4[rr][qq] = ((const float4*)W_out)[(4 * li + rr) * 4 + qq];
    const float4 bo4 = ((const float4*)b_out)[li];
    const int nb = blockIdx.x * 256;

    #pragma unroll
    for (int it = 0; it < 16; it++) {
        int ln = it * 16 + w * 4 + g;
        int n2 = nb + ln;
        if (n2 < NNODES) {
            const float4* hq = (const float4*)(hn_s + ln * 20);
            float4 h0 = hq[0], h1 = hq[1], h2 = hq[2], h3 = hq[3];
            float4 o;
            o.x = bo4.x + w4[0][0].x*h0.x + w4[0][0].y*h0.y + w4[0][0].z*h0.z + w4[0][0].w*h0.w
                        + w4[0][1].x*h1.x + w4[0][1].y*h1.y + w4[0][1].z*h1.z + w4[0][1].w*h1.w
                        + w4[0][2].x*h2.x + w4[0][2].y*h2.y + w4[0][2].z*h2.z + w4[0][2].w*h2.w
                        + w4[0][3].x*h3.x + w4[0][3].y*h3.y + w4[0][3].z*h3.z + w4[0][3].w*h3.w;
            o.y = bo4.y + w4[1][0].x*h0.x + w4[1][0].y*h0.y + w4[1][0].z*h0.z + w4[1][0].w*h0.w
                        + w4[1][1].x*h1.x + w4[1][1].y*h1.y + w4[1][1].z*h1.z + w4[1][1].w*h1.w
                        + w4[1][2].x*h2.x + w4[1][2].y*h2.y + w4[1][2].z*h2.z + w4[1][2].w*h2.w
                        + w4[1][3].x*h3.x + w4[1][3].y*h3.y + w4[1][3].z*h3.z + w4[1][3].w*h3.w;
            o.z = bo4.z + w4[2][0].x*h0.x + w4[2][0].y*h0.y + w4[2][0].z*h0.z + w4[2][0].w*h0.w
                        + w4[2][1].x*h1.x + w4[2][1].y*h1.y + w4[2][1].z*h1.z + w4[2][1].w*h1.w
                        + w4[2][2].x*h2.x + w4[2][2].y*h2.y + w4[2][2].z*h2.z + w4[2][2].w*h2.w
                        + w4[2][3].x*h3.x + w4[2][3].y*h3.y + w4[2][3].z*h3.z + w4[2][3].w*h3.w;
            o.w = bo4.w + w4[3][0].x*h0.x + w4[3][0].y*h0.y + w4[3][0].z*h0.z + w4[3][0].w*h0.w
                        + w4[3][1].x*h1.x + w4[3][1].y*h1.y + w4[3][1].z*h1.z + w4[3][1].w*h1.w
                        + w4[3][2].x*h2.x + w4[3][2].y*h2.y + w4[3][2].z*h2.z + w4[3][2].w*h2.w
                        + w4[3][3].x*h3.x + w4[3][3].y*h3.y + w4[3][3].z*h3.z + w4[3][3].w*h3.w;
            ((float4*)(out + (size_t)n2 * NCLS))[li] = o;
        }
    }
}

extern "C" void kernel_launch(void* const* d_in, const int* in_sizes, int n_in,
                              void* d_out, int out_size, void* d_ws, size_t ws_size,
                              hipStream_t stream) {
    const float* feat     = (const float*)d_in[0];
    const int*   src      = (const int*)d_in[1];
    const int*   dst      = (const int*)d_in[2];
    const int*   etype    = (const int*)d_in[3];
    const float* edge_emb = (const float*)d_in[4];
    const float* W_ih     = (const float*)d_in[5];
    const float* W_hh     = (const float*)d_in[6];
    const float* b_ih     = (const float*)d_in[7];
    const float* b_hh     = (const float*)d_in[8];
    const float* W_out    = (const float*)d_in[9];
    const float* b_out    = (const float*)d_in[10];
    float* out = (float*)d_out;

    // workspace layout (4-byte elements): ~13.8 MB
    float* magg   = (float*)d_ws;                         // NNODES*16
    int*   offmat = (int*)d_ws + (size_t)NNODES * MSG;    // M_SCAN
    int*   bsum   = offmat + M_SCAN;                      // 256 (NSB used)
    int*   bnd    = bsum + 256;                           // 1024 (NBK+1 used)
    int*   cb     = bnd + 1024;                           // NCHK
    int*   rec    = cb + NCHK;                            // NEDGES
    size_t need   = ((size_t)NNODES * MSG + M_SCAN + 256 + 1024 + NCHK + NEDGES) * 4;

    hipMemsetAsync(magg, 0, (size_t)NNODES * MSG * sizeof(float), stream);
    if (ws_size >= need) {
        hist_k    <<<NCH, 1024, 0, stream>>>(dst, offmat);
        scan_bsum <<<NSB, 256, 0, stream>>>(offmat, bsum);
        scan_write<<<NSB, 256, 0, stream>>>(bsum, offmat, bnd);
        scatter_k <<<NCH, 1024, 0, stream>>>(src, dst, etype, offmat, rec);
        sort2_k   <<<NBK, 256, 0, stream>>>(bnd, rec, cb);
        agg2_k    <<<AGG2_BLOCKS, 256, 0, stream>>>(feat, rec, bnd, cb, edge_emb, magg);
    } else {
        ggnn_edge<<<2560, 256, 0, stream>>>(feat, src, dst, etype, edge_emb, magg);
    }
    node_k<<<(NNODES + 255) / 256, 256, 0, stream>>>(
        feat, magg, W_ih, W_hh, b_ih, b_hh, W_out, b_out, out);
}